// Round 6
// baseline (119.484 us; speedup 1.0000x reference)
//
#include <hip/hip_runtime.h>

// PiecewiseSparseMLP: B=262144 rows, K=32 experts (10 -> 20 -> 1), distance-softmax gating.
// Round 6: 4 rows/thread (quarters per-row LDS broadcast-read + weight-extract cost),
// 4-way expert split, block=512 -> 512 rows/block, grid=512 (2 blocks/CU, 1 round).
// __launch_bounds__(512,4) -> 128-VGPR budget: room for ~95 live regs, no R4 spill storm.

#define KX 32
#define DIN 10
#define DH 20
#define GRP 128            // threads per expert-group (2 waves)
#define NROW 4             // rows per thread
#define RPB (GRP * NROW)   // 512 rows per block
#define BLOCK 512

typedef float v2f __attribute__((ext_vector_type(2)));

__global__ __launch_bounds__(BLOCK, 4) void moe_kernel(
    const float* __restrict__ x,      // [B,10]
    const float* __restrict__ W1,     // [32,20,10] = [k][200] contiguous
    const float* __restrict__ b1,     // [32,20]
    const float* __restrict__ W2,     // [32,1,20]
    const float* __restrict__ b2,     // [32]
    const float* __restrict__ proto,  // [32,10]
    float* __restrict__ out,          // [B]
    int B)
{
    __shared__ float4 s_w1[KX * 50];       // W1 verbatim
    __shared__ float4 s_bw[KX * 10];       // {b1[j], w2[j]} interleaved
    __shared__ float4 s_pr[KX * 3];        // proto padded 10->12
    __shared__ float  s_b2[KX];
    __shared__ float4 s_red[3 * GRP * 2];  // per group: {num0..3, den0..3} as 2 float4

    const int tid = threadIdx.x;

    // ---- stage weights to LDS (one-time, coalesced) ----
    {
        const float4* gW1 = (const float4*)W1;
        for (int t = tid; t < KX * 50; t += BLOCK) s_w1[t] = gW1[t];
        float2* bw = (float2*)s_bw;
        for (int t = tid; t < KX * DH; t += BLOCK) bw[t] = make_float2(b1[t], W2[t]);
        float* pr = (float*)s_pr;
        for (int t = tid; t < KX * DIN; t += BLOCK) {
            const int row = t / DIN;
            pr[row * 12 + (t - row * DIN)] = proto[t];
        }
        if (tid < KX) s_b2[tid] = b2[tid];
    }

    const int rl = tid & (GRP - 1);
    // wave-uniform expert-group selector (waves 2g,2g+1 -> group g)
    const int g = __builtin_amdgcn_readfirstlane(tid >> 7);
    const int k0 = g * (KX / 4);

    const int rbase = blockIdx.x * RPB + rl;

    v2f xr[NROW][5];
#pragma unroll
    for (int rr = 0; rr < NROW; ++rr) {
        int r = rbase + rr * GRP;
        if (r >= B) r = B - 1;               // grid sized exactly; benign clamp
        const float2* gx = (const float2*)(x + (size_t)r * DIN);
#pragma unroll
        for (int i = 0; i < 5; ++i) { float2 t = gx[i]; xr[rr][i] = v2f{t.x, t.y}; }
    }

    __syncthreads();

    float num[NROW], den[NROW];
#pragma unroll
    for (int rr = 0; rr < NROW; ++rr) { num[rr] = 0.f; den[rr] = 0.f; }

#pragma unroll 1
    for (int kk = 0; kk < KX / 4; ++kk) {
        const int k = k0 + kk;

        // ---- gating for all rows ----
        const float4 p0 = s_pr[k * 3 + 0];
        const float4 p1 = s_pr[k * 3 + 1];
        const float4 p2 = s_pr[k * 3 + 2];
        v2f dv[NROW];
#pragma unroll
        for (int rr = 0; rr < NROW; ++rr) dv[rr] = v2f{0.f, 0.f};
        {
            const v2f pv[5] = { v2f{p0.x, p0.y}, v2f{p0.z, p0.w},
                                v2f{p1.x, p1.y}, v2f{p1.z, p1.w},
                                v2f{p2.x, p2.y} };
#pragma unroll
            for (int i = 0; i < 5; ++i) {
#pragma unroll
                for (int rr = 0; rr < NROW; ++rr) {
                    const v2f d = xr[rr][i] - pv[i];
                    dv[rr] = __builtin_elementwise_fma(d, d, dv[rr]);
                }
            }
        }
        float gate[NROW], pred[NROW];
        const float bk2 = s_b2[k];
#pragma unroll
        for (int rr = 0; rr < NROW; ++rr) {
            gate[rr] = __expf(-__fsqrt_rn(dv[rr].x + dv[rr].y));
            pred[rr] = bk2;
        }

        // ---- expert MLP, hidden pairs: 5 W1 f4 reads serve ALL 4 rows ----
        const float4* wk = &s_w1[k * 50];
        const float4* bwk = &s_bw[k * 10];
#pragma unroll 2
        for (int j2 = 0; j2 < DH / 2; ++j2) {
            // chunk 1: hidden unit 2*j2 (weights A, Bq, C.xy)
            const float4 A  = wk[j2 * 5 + 0];
            const float4 Bq = wk[j2 * 5 + 1];
            const float4 C  = wk[j2 * 5 + 2];
            v2f a0[NROW];
#pragma unroll
            for (int rr = 0; rr < NROW; ++rr) a0[rr] = v2f{0.f, 0.f};
            {
                const v2f w0 = v2f{A.x, A.y}, w1v = v2f{A.z, A.w},
                          w2v = v2f{Bq.x, Bq.y}, w3 = v2f{Bq.z, Bq.w},
                          w4 = v2f{C.x, C.y};
#pragma unroll
                for (int rr = 0; rr < NROW; ++rr) {
                    a0[rr] = __builtin_elementwise_fma(w0,  xr[rr][0], a0[rr]);
                    a0[rr] = __builtin_elementwise_fma(w1v, xr[rr][1], a0[rr]);
                    a0[rr] = __builtin_elementwise_fma(w2v, xr[rr][2], a0[rr]);
                    a0[rr] = __builtin_elementwise_fma(w3,  xr[rr][3], a0[rr]);
                    a0[rr] = __builtin_elementwise_fma(w4,  xr[rr][4], a0[rr]);
                }
            }
            // chunk 2: hidden unit 2*j2+1 (weights C.zw, D, E)
            const float4 D = wk[j2 * 5 + 3];
            const float4 E = wk[j2 * 5 + 4];
            v2f a1[NROW];
#pragma unroll
            for (int rr = 0; rr < NROW; ++rr) a1[rr] = v2f{0.f, 0.f};
            {
                const v2f u0 = v2f{C.z, C.w}, u1 = v2f{D.x, D.y},
                          u2 = v2f{D.z, D.w}, u3 = v2f{E.x, E.y},
                          u4 = v2f{E.z, E.w};
#pragma unroll
                for (int rr = 0; rr < NROW; ++rr) {
                    a1[rr] = __builtin_elementwise_fma(u0, xr[rr][0], a1[rr]);
                    a1[rr] = __builtin_elementwise_fma(u1, xr[rr][1], a1[rr]);
                    a1[rr] = __builtin_elementwise_fma(u2, xr[rr][2], a1[rr]);
                    a1[rr] = __builtin_elementwise_fma(u3, xr[rr][3], a1[rr]);
                    a1[rr] = __builtin_elementwise_fma(u4, xr[rr][4], a1[rr]);
                }
            }

            const float4 bwv = bwk[j2];  // {b1[2j2], w2[2j2], b1[2j2+1], w2[2j2+1]}
#pragma unroll
            for (int rr = 0; rr < NROW; ++rr) {
                float h;
                h = a0[rr].x + a0[rr].y + bwv.x; h = fmaxf(h, 0.f);
                pred[rr] = fmaf(bwv.y, h, pred[rr]);
                h = a1[rr].x + a1[rr].y + bwv.z; h = fmaxf(h, 0.f);
                pred[rr] = fmaf(bwv.w, h, pred[rr]);
            }
        }

#pragma unroll
        for (int rr = 0; rr < NROW; ++rr) {
            num[rr] = fmaf(pred[rr], gate[rr], num[rr]);
            den[rr] += gate[rr];
        }
    }

    // ---- cross-group reduction ----
    if (g) {
        s_red[((g - 1) * GRP + rl) * 2 + 0] = make_float4(num[0], num[1], num[2], num[3]);
        s_red[((g - 1) * GRP + rl) * 2 + 1] = make_float4(den[0], den[1], den[2], den[3]);
    }
    __syncthreads();
    if (g == 0) {
#pragma unroll
        for (int p = 0; p < 3; ++p) {
            const float4 tn = s_red[(p * GRP + rl) * 2 + 0];
            const float4 td = s_red[(p * GRP + rl) * 2 + 1];
            num[0] += tn.x; num[1] += tn.y; num[2] += tn.z; num[3] += tn.w;
            den[0] += td.x; den[1] += td.y; den[2] += td.z; den[3] += td.w;
        }
#pragma unroll
        for (int rr = 0; rr < NROW; ++rr) {
            const int r = rbase + rr * GRP;
            if (r < B) out[r] = num[rr] / den[rr];
        }
    }
}

extern "C" void kernel_launch(void* const* d_in, const int* in_sizes, int n_in,
                              void* d_out, int out_size, void* d_ws, size_t ws_size,
                              hipStream_t stream) {
    const float* x     = (const float*)d_in[0];
    const float* W1    = (const float*)d_in[1];
    const float* b1    = (const float*)d_in[2];
    const float* W2    = (const float*)d_in[3];
    const float* b2    = (const float*)d_in[4];
    const float* proto = (const float*)d_in[5];
    float* out = (float*)d_out;

    const int B = out_size;  // D_OUT = 1
    const int grid = (B + RPB - 1) / RPB;
    hipLaunchKernelGGL(moe_kernel, dim3(grid), dim3(BLOCK), 0, stream,
                       x, W1, b1, W2, b2, proto, out, B);
}

// Round 7
// 104.915 us; speedup vs baseline: 1.1389x; 1.1389x over previous
//
#include <hip/hip_runtime.h>

// PiecewiseSparseMLP: B=262144 rows, K=32 experts (10 -> 20 -> 1), distance-softmax gating.
// Round 7: MFMA rewrite. Per 32-row tile: 1 gating MFMA (all 32 protos) + 32 layer1
// MFMAs (one per expert; b1 folded into K-slot 10 via x_ext[10]=1). Epilogue uses the
// verified 32x32 C/D layout: col=lane&31 (batch row), m=(reg&3)+8*(reg>>2)+4*(lane>>5).
// Experts paired (e, e+4) across lane halves so gate*pred needs one cndmask.
// Block=256 (4 waves), 2 tiles/wave, grid=1024 -> 4 blocks/CU, LDS 37 KB.

#define KX 32
#define DIN 10
#define DH 20

typedef short bf16x8 __attribute__((ext_vector_type(8)));
typedef float f32x16 __attribute__((ext_vector_type(16)));

#define ZERO16 {0.f,0.f,0.f,0.f, 0.f,0.f,0.f,0.f, 0.f,0.f,0.f,0.f, 0.f,0.f,0.f,0.f}

__device__ inline unsigned short f2bf(float f) {   // fp32 -> bf16 RNE
    unsigned int u = __float_as_uint(f);
    unsigned int r = u + 0x7fffu + ((u >> 16) & 1u);
    return (unsigned short)(r >> 16);
}

union BFU { bf16x8 v; unsigned short s[8]; };

__global__ __launch_bounds__(256, 4) void moe_kernel(
    const float* __restrict__ x,      // [B,10]
    const float* __restrict__ W1,     // [32,20,10]
    const float* __restrict__ b1,     // [32,20]
    const float* __restrict__ W2,     // [32,1,20]
    const float* __restrict__ b2,     // [32]
    const float* __restrict__ proto,  // [32,10]
    float* __restrict__ out,          // [B]
    int B)
{
    __shared__ bf16x8 s_af[KX * 64];   // A-frag per expert per lane (32 KB)
    __shared__ float  s_w2[KX * 32];   // [e][half*16+reg] -> W2 in C-layout order (4 KB)
    __shared__ bf16x8 s_pf[64];        // proto A-frag (1 KB)
    __shared__ float  s_pn2[32];       // ||proto||^2 in [half*16+reg] order (128 B)

    const int tid = threadIdx.x;

    // ---- build LDS tables (weights are tiny; L2-cached re-reads per block) ----
    for (int idx = tid; idx < KX * 64; idx += 256) {
        const int e = idx >> 6, l = idx & 63;
        const int m = l & 31, kb = (l >> 5) * 8;
        BFU u;
#pragma unroll
        for (int j = 0; j < 8; ++j) {
            const int kk = kb + j;
            float v = 0.f;
            if (m < DH) {
                if (kk < DIN) v = W1[(e * DH + m) * DIN + kk];
                else if (kk == DIN) v = b1[e * DH + m];   // bias slot (x_ext[10]=1)
            }
            u.s[j] = f2bf(v);
        }
        s_af[idx] = u.v;
    }
    for (int idx = tid; idx < KX * 32; idx += 256) {
        const int e = idx >> 5, rem = idx & 31;
        const int half = rem >> 4, reg = rem & 15;
        const int hid = (reg & 3) + 8 * (reg >> 2) + 4 * half;
        s_w2[idx] = (hid < DH) ? W2[e * DH + hid] : 0.f;
    }
    if (tid < 64) {
        const int m = tid & 31, kb = (tid >> 5) * 8;
        BFU u;
#pragma unroll
        for (int j = 0; j < 8; ++j) {
            const int kk = kb + j;
            u.s[j] = f2bf(kk < DIN ? proto[m * DIN + kk] : 0.f);  // slot 10 = 0
        }
        s_pf[tid] = u.v;
    }
    if (tid < 32) {
        const int half = tid >> 4, reg = tid & 15;
        const int p = (reg & 3) + 8 * (reg >> 2) + 4 * half;
        float s = 0.f;
#pragma unroll
        for (int i = 0; i < DIN; ++i) { const float v = proto[p * DIN + i]; s = fmaf(v, v, s); }
        s_pn2[tid] = s;
    }
    __syncthreads();

    const int lane = tid & 63;
    const int wave = tid >> 6;
    const int half = lane >> 5;
    const int col  = lane & 31;
    const bf16x8 pfrag = s_pf[lane];
    const float* pn2h = s_pn2 + half * 16;
    const float* w2base = s_w2 + half * 16;

    for (int t = 0; t < 2; ++t) {
        const int tileIdx = (blockIdx.x * 4 + wave) * 2 + t;
        const int row = tileIdx * 32 + col;
        const int rr = (row < B) ? row : (B - 1);

        // ---- build B-frag: x_ext[rr][kb..kb+7], kb = half*8; slot10 = 1.0 ----
        float xe[8];
        const float* xr = x + (size_t)rr * DIN;
        if (half == 0) {
#pragma unroll
            for (int i = 0; i < 4; ++i) {
                const float2 v = *(const float2*)(xr + 2 * i);
                xe[2 * i] = v.x; xe[2 * i + 1] = v.y;
            }
        } else {
            const float2 v = *(const float2*)(xr + 8);
            xe[0] = v.x; xe[1] = v.y; xe[2] = 1.f;
            xe[3] = 0.f; xe[4] = 0.f; xe[5] = 0.f; xe[6] = 0.f; xe[7] = 0.f;
        }
        BFU xu;
#pragma unroll
        for (int j = 0; j < 8; ++j) xu.s[j] = f2bf(xe[j]);
        const bf16x8 xfrag = xu.v;

        // ||x||^2 (fp32): half0 sums its 8, half1 only x[8],x[9] (slot 1.0 excluded)
        float part;
        if (half == 0) {
            part = 0.f;
#pragma unroll
            for (int j = 0; j < 8; ++j) part = fmaf(xe[j], xe[j], part);
        } else {
            part = fmaf(xe[0], xe[0], xe[1] * xe[1]);
        }
        const float xn2 = part + __shfl_xor(part, 32);

        // ---- gating MFMA: dot[p, r] for all 32 protos ----
        f32x16 zg = ZERO16;
        const f32x16 dotg = __builtin_amdgcn_mfma_f32_32x32x16_bf16(pfrag, xfrag, zg, 0, 0, 0);

        float gate[16];
#pragma unroll
        for (int q = 0; q < 16; ++q) {
            float d2 = fmaf(dotg[q], -2.f, xn2 + pn2h[q]);
            d2 = fmaxf(d2, 0.f);
            gate[q] = __expf(-__fsqrt_rn(d2));
        }

        // ---- expert loop: pairs (elo, elo+4) across lane halves ----
        float accn[16];
#pragma unroll 2
        for (int j = 0; j < 16; ++j) {
            const int elo = (j & 3) + 8 * (j >> 2);
            const int ehi = elo + 4;
            const bf16x8 alo = s_af[elo * 64 + lane];
            const bf16x8 ahi = s_af[ehi * 64 + lane];
            f32x16 z0 = ZERO16, z1 = ZERO16;
            const f32x16 clo = __builtin_amdgcn_mfma_f32_32x32x16_bf16(alo, xfrag, z0, 0, 0, 0);
            const f32x16 chi = __builtin_amdgcn_mfma_f32_32x32x16_bf16(ahi, xfrag, z1, 0, 0, 0);
            const float* w2lo = w2base + elo * 32;
            const float* w2hi = w2base + ehi * 32;
            float pplo = 0.f, pphi = 0.f;
#pragma unroll
            for (int q = 0; q < 16; ++q) {
                pplo = fmaf(fmaxf(clo[q], 0.f), w2lo[q], pplo);
                pphi = fmaf(fmaxf(chi[q], 0.f), w2hi[q], pphi);
            }
            const float plo = pplo + __shfl_xor(pplo, 32);
            const float phi = pphi + __shfl_xor(pphi, 32);
            const float pred = half ? (phi + b2[ehi]) : (plo + b2[elo]);
            accn[j] = gate[j] * pred;
        }

        // ---- finalize: sum over this half's 16 experts, then cross-half ----
        float nsum = 0.f, dsum = 0.f;
#pragma unroll
        for (int q = 0; q < 16; ++q) { nsum += accn[q]; dsum += gate[q]; }
        nsum += __shfl_xor(nsum, 32);
        dsum += __shfl_xor(dsum, 32);
        if (half == 0 && row < B) out[row] = nsum / dsum;
    }
}

extern "C" void kernel_launch(void* const* d_in, const int* in_sizes, int n_in,
                              void* d_out, int out_size, void* d_ws, size_t ws_size,
                              hipStream_t stream) {
    const float* x     = (const float*)d_in[0];
    const float* W1    = (const float*)d_in[1];
    const float* b1    = (const float*)d_in[2];
    const float* W2    = (const float*)d_in[3];
    const float* b2    = (const float*)d_in[4];
    const float* proto = (const float*)d_in[5];
    float* out = (float*)d_out;

    const int B = out_size;                 // D_OUT = 1
    const int rows_per_block = 4 * 2 * 32;  // 4 waves x 2 tiles x 32 rows = 256
    const int grid = (B + rows_per_block - 1) / rows_per_block;
    hipLaunchKernelGGL(moe_kernel, dim3(grid), dim3(256), 0, stream,
                       x, W1, b1, W2, b2, proto, out, B);
}